// Round 2
// baseline (564.592 us; speedup 1.0000x reference)
//
#include <hip/hip_runtime.h>

// Problem constants (match reference)
constexpr int BB = 32;      // batches
constexpr int NN = 4096;    // rows per batch
constexpr int DD = 512;     // feature dim
constexpr int CC = 64;      // clusters/anchors

constexpr int BM = 64;      // rows per block (k1)
constexpr int BK = 16;      // K-chunk (k1)
constexpr int MROWS = BB * NN;        // 131072
constexpr int NBLK1 = MROWS / BM;     // 2048

// workspace layout (float elements)
constexpr size_t WS_SCORES = 0;                             // [BB][CC][NN] f32 (32 MB)
constexpr size_t WS_INVN   = (size_t)BB * CC * NN;          // [BB][NN] f32
constexpr size_t WS_COUNTS = WS_INVN + (size_t)BB * NN;     // [BB][CC] int
constexpr size_t WS_INDEX  = WS_COUNTS + (size_t)BB * CC;   // [BB] int
constexpr size_t WS_ANORM  = WS_INDEX + BB;                 // [CC] f32
// total ~8.52M floats = ~32.5 MiB

// ---------------- k0: zero out + counts, compute anchor squared norms ----------------
__global__ __launch_bounds__(256) void k0_init(const float* __restrict__ anchors,
                                               float* __restrict__ out,
                                               int* __restrict__ counts,
                                               float* __restrict__ anorm2)
{
    int t = blockIdx.x * 256 + threadIdx.x;
    if (t < BB * DD) out[t] = 0.0f;
    if (t < BB * CC) counts[t] = 0;
    if (blockIdx.x == 0 && threadIdx.x < CC) {
        const float4* a = (const float4*)(anchors + (size_t)threadIdx.x * DD);
        float s = 0.f;
        for (int i = 0; i < DD / 4; ++i) {
            float4 v = a[i];
            s += v.x * v.x + v.y * v.y + v.z * v.z + v.w * v.w;
        }
        anorm2[threadIdx.x] = s;
    }
}

// ---------------- k1: dots + norms + softmax scores + argmin counts ----------------
// Block: 256 threads, 64 rows x 64 anchors. K staged in BK=16 chunks.
// Microtile 4 rows x 4 anchors per thread (tc = tid>>4 anchor group, tm = tid&15 row group).
__global__ __launch_bounds__(256) void k1_scores(
    const float* __restrict__ x, const int* __restrict__ mask,
    const float* __restrict__ anchors, const float* __restrict__ anorm2,
    float* __restrict__ scoresT, float* __restrict__ invn,
    int* __restrict__ counts)
{
    __shared__ float xt[BK][BM + 4];   // +4 pad: staging writes 2-way banks only
    __shared__ float at[BK][CC + 4];
    __shared__ float dl[BM][CC + 4];   // dots, row stride 68 floats (16B aligned)
    __shared__ float rssq[BM];
    __shared__ float an2[CC];

    const int t = threadIdx.x;
    const int brow = blockIdx.x * BM;
    const int srow = t >> 2;   // 0..63 (staging row / epilogue row)
    const int kq   = t & 3;    // 0..3  (staging k-quarter / epilogue c-quarter)
    const int tc   = t >> 4;   // 0..15 anchor group (4 anchors)
    const int tm   = t & 15;   // 0..15 row group (4 rows)

    if (t < CC) an2[t] = anorm2[t];

    const float* xp = x + (size_t)(brow + srow) * DD + kq * 4;
    const float* ap = anchors + (size_t)srow * DD + kq * 4;

    float acc[4][4] = {};
    float ssq = 0.f;

    float4 xv = *(const float4*)(xp);
    float4 av = *(const float4*)(ap);

    for (int kb = 0; kb < DD; kb += BK) {
        ssq += xv.x * xv.x + xv.y * xv.y + xv.z * xv.z + xv.w * xv.w;
        xt[kq * 4 + 0][srow] = xv.x; xt[kq * 4 + 1][srow] = xv.y;
        xt[kq * 4 + 2][srow] = xv.z; xt[kq * 4 + 3][srow] = xv.w;
        at[kq * 4 + 0][srow] = av.x; at[kq * 4 + 1][srow] = av.y;
        at[kq * 4 + 2][srow] = av.z; at[kq * 4 + 3][srow] = av.w;
        __syncthreads();
        if (kb + BK < DD) {   // prefetch next chunk into registers (hides HBM latency)
            xv = *(const float4*)(xp + kb + BK);
            av = *(const float4*)(ap + kb + BK);
        }
        #pragma unroll
        for (int k = 0; k < BK; ++k) {
            float4 xf = *(const float4*)&xt[k][tm * 4];
            float4 af = *(const float4*)&at[k][tc * 4];
            float xr[4] = {xf.x, xf.y, xf.z, xf.w};
            float ar[4] = {af.x, af.y, af.z, af.w};
            #pragma unroll
            for (int i = 0; i < 4; ++i)
                #pragma unroll
                for (int j = 0; j < 4; ++j)
                    acc[i][j] += xr[i] * ar[j];
        }
        __syncthreads();
    }

    // row sum-of-squares: the 4 staging lanes of each row hold disjoint k-slices
    ssq += __shfl_xor(ssq, 1);
    ssq += __shfl_xor(ssq, 2);
    if (kq == 0) rssq[srow] = ssq;

    // park dots in LDS for the per-row epilogue
    #pragma unroll
    for (int i = 0; i < 4; ++i) {
        float4 v4 = make_float4(acc[i][0], acc[i][1], acc[i][2], acc[i][3]);
        *(float4*)&dl[tm * 4 + i][tc * 4] = v4;
    }
    __syncthreads();

    // epilogue: 4 lanes (kq) per row (srow), 16 clusters each
    const int r = srow;
    const int q = kq;
    const int gn = brow + r;
    const int b  = gn >> 12;         // N = 4096
    const int n  = gn & (NN - 1);
    const float ss = rssq[r];
    float nrm = fmaxf(sqrtf(ss), 1e-12f);   // F.normalize eps
    const float inv  = 1.0f / nrm;
    const float ssqn = ss * inv * inv;      // == sum(xn*xn), mirrors reference

    float v[16];
    float vmax = -3.4e38f;
    #pragma unroll
    for (int j = 0; j < 16; ++j) {
        const int c = q * 16 + j;
        float dot = dl[r][c] * inv;
        float sq = fmaxf(ssqn + an2[c] - 2.0f * dot, 0.0f);
        float dist = sqrtf(sq);
        float vv = 1.0f / dist;
        v[j] = vv;
        vmax = fmaxf(vmax, vv);
    }
    // local argmax (ascending c, strict > keeps FIRST max like jnp.argmax)
    float bv = v[0]; int bc = q * 16;
    #pragma unroll
    for (int j = 1; j < 16; ++j)
        if (v[j] > bv) { bv = v[j]; bc = q * 16 + j; }

    vmax = fmaxf(vmax, __shfl_xor(vmax, 1));
    vmax = fmaxf(vmax, __shfl_xor(vmax, 2));
    float s = 0.f;
    #pragma unroll
    for (int j = 0; j < 16; ++j) { float e = __expf(v[j] - vmax); v[j] = e; s += e; }
    s += __shfl_xor(s, 1);
    s += __shfl_xor(s, 2);
    const float rs = 1.0f / s;

    // cross-lane argmax combine (tie -> smaller c; lane c-ranges are ordered by q)
    #pragma unroll
    for (int d = 1; d <= 2; d <<= 1) {
        float ov = __shfl_xor(bv, d);
        int   oc = __shfl_xor(bc, d);
        if (ov > bv || (ov == bv && oc < bc)) { bv = ov; bc = oc; }
    }

    const bool valid = (n < mask[b]);
    const float vm = valid ? 1.0f : 0.0f;   // invalid rows -> score 0 (matches where())
    float* so = scoresT + ((size_t)b * CC) * NN + n;
    #pragma unroll
    for (int j = 0; j < 16; ++j)
        so[(size_t)(q * 16 + j) * NN] = v[j] * rs * vm;

    if (q == 0) {
        invn[gn] = inv;
        if (valid) atomicAdd(&counts[b * CC + bc], 1);
    }
}

// ---------------- k2: per-batch mode cluster (argmax of counts, first-index tie) ----------------
__global__ void k2_index(const int* __restrict__ counts, int* __restrict__ index)
{
    const int c = threadIdx.x;   // 64 threads = 1 wave
    for (int b = 0; b < BB; ++b) {
        int cnt = counts[b * CC + c];
        int bc = c;
        #pragma unroll
        for (int d = 1; d < 64; d <<= 1) {
            int ocnt = __shfl_xor(cnt, d);
            int oc   = __shfl_xor(bc, d);
            if (ocnt > cnt || (ocnt == cnt && oc < bc)) { cnt = ocnt; bc = oc; }
        }
        if (c == 0) index[b] = bc;
    }
}

// ---------------- k3: feature[b][d] = sum_n x[b][n][d] * inv[n] * score[b][n][index[b]] ----------------
constexpr int NCHUNK = 16;
constexpr int CROWS = NN / NCHUNK;   // 256 rows per block
__global__ __launch_bounds__(256) void k3_feature(
    const float* __restrict__ x, const float* __restrict__ scoresT,
    const float* __restrict__ invn, const int* __restrict__ index,
    float* __restrict__ out)
{
    __shared__ float w[CROWS];
    const int t  = threadIdx.x;
    const int b  = blockIdx.x >> 4;
    const int ch = blockIdx.x & (NCHUNK - 1);
    const int n0 = ch * CROWS;
    const int idx = index[b];
    {
        const int n = n0 + t;
        float sc = scoresT[((size_t)(b * CC + idx)) * NN + n];  // already 0 for invalid rows
        w[t] = sc * invn[(size_t)b * NN + n];
    }
    __syncthreads();

    float ax = 0.f, ay = 0.f;
    const float* xb = x + ((size_t)b * NN + n0) * DD + t * 2;   // thread owns d = 2t, 2t+1
    for (int r0 = 0; r0 < CROWS; r0 += 8) {
        #pragma unroll
        for (int u = 0; u < 8; ++u) {
            float2 xv = *(const float2*)(xb + (size_t)(r0 + u) * DD);
            float ww = w[r0 + u];
            ax += xv.x * ww;
            ay += xv.y * ww;
        }
    }
    atomicAdd(&out[b * DD + t * 2],     ax);
    atomicAdd(&out[b * DD + t * 2 + 1], ay);
}

// ---------------- launcher ----------------
extern "C" void kernel_launch(void* const* d_in, const int* in_sizes, int n_in,
                              void* d_out, int out_size, void* d_ws, size_t ws_size,
                              hipStream_t stream)
{
    const float* x       = (const float*)d_in[0];
    const int*   mask    = (const int*)d_in[1];
    const float* anchors = (const float*)d_in[2];
    float* out = (float*)d_out;

    float* wsf     = (float*)d_ws;
    float* scoresT = wsf + WS_SCORES;
    float* invn    = wsf + WS_INVN;
    int*   counts  = (int*)(wsf + WS_COUNTS);
    int*   index   = (int*)(wsf + WS_INDEX);
    float* anorm2  = wsf + WS_ANORM;

    hipLaunchKernelGGL(k0_init,  dim3(64),           dim3(256), 0, stream,
                       anchors, out, counts, anorm2);
    hipLaunchKernelGGL(k1_scores, dim3(NBLK1),       dim3(256), 0, stream,
                       x, mask, anchors, anorm2, scoresT, invn, counts);
    hipLaunchKernelGGL(k2_index, dim3(1),            dim3(64),  0, stream,
                       counts, index);
    hipLaunchKernelGGL(k3_feature, dim3(BB * NCHUNK), dim3(256), 0, stream,
                       x, scoresT, invn, index, out);
}

// Round 3
// 553.947 us; speedup vs baseline: 1.0192x; 1.0192x over previous
//
#include <hip/hip_runtime.h>

// Problem constants (match reference)
constexpr int BB = 32;      // batches
constexpr int NN = 4096;    // rows per batch
constexpr int DD = 512;     // feature dim
constexpr int CC = 64;      // clusters/anchors

constexpr int BM = 128;     // rows per block (k1)
constexpr int BK = 32;      // K-chunk (k1)
constexpr int MROWS = BB * NN;        // 131072
constexpr int NBLK1 = MROWS / BM;     // 1024

// workspace layout (float elements)
constexpr size_t WS_SCORES = 0;                             // [B][N][C] f32 (32 MB)
constexpr size_t WS_INVN   = (size_t)BB * NN * CC;          // [B][N] f32
constexpr size_t WS_COUNTS = WS_INVN + (size_t)BB * NN;     // [B][C] int
constexpr size_t WS_INDEX  = WS_COUNTS + (size_t)BB * CC;   // [B] int
constexpr size_t WS_ANORM  = WS_INDEX + BB;                 // [C] f32

// ---------------- k0: zero out + counts, compute anchor squared norms ----------------
__global__ __launch_bounds__(256) void k0_init(const float* __restrict__ anchors,
                                               float* __restrict__ out,
                                               int* __restrict__ counts,
                                               float* __restrict__ anorm2)
{
    int t = blockIdx.x * 256 + threadIdx.x;
    if (t < BB * DD) out[t] = 0.0f;
    if (t < BB * CC) counts[t] = 0;
    if (blockIdx.x == 0 && threadIdx.x < CC) {
        const float4* a = (const float4*)(anchors + (size_t)threadIdx.x * DD);
        float s = 0.f;
        #pragma unroll 8
        for (int i = 0; i < DD / 4; ++i) {
            float4 v = a[i];
            s += v.x * v.x + v.y * v.y + v.z * v.z + v.w * v.w;
        }
        anorm2[threadIdx.x] = s;
    }
}

// ---------------- k1: dots + norms + softmax scores + argmin counts ----------------
// 256 threads, tile 128 rows x 64 anchors, BK=32.
// Compute mapping: tc = t&15 (anchors tc*4..+3), tm = t>>4 (rows tm*8..+7).
// Row R's 64 dots live in the 16 consecutive lanes t = (R>>3)*16 + tc (same wave)
// -> all softmax/argmax reductions are __shfl_xor(1,2,4,8), no LDS epilogue.
__global__ __launch_bounds__(256) void k1_scores(
    const float* __restrict__ x, const int* __restrict__ mask,
    const float* __restrict__ anchors, const float* __restrict__ anorm2,
    float* __restrict__ scores, float* __restrict__ invn,
    int* __restrict__ counts)
{
    __shared__ float xt[BK][BM + 4];   // [32][132] transposed x tile; stride 132 -> 2-way banks on stage, conflict-free b128 reads
    __shared__ float at[BK][CC + 4];   // [32][68]
    __shared__ float rssq[BM];
    __shared__ float an2s[CC];

    const int t    = threadIdx.x;
    const int brow = blockIdx.x * BM;
    const int b    = brow >> 12;           // whole block is in one batch (4096 % 128 == 0)
    const int n0   = brow & (NN - 1);
    const int tc   = t & 15;               // anchor group
    const int tm   = t >> 4;               // row group

    // staging roles
    const int sxrow = t >> 1;              // 0..127: x row
    const int sxk   = (t & 1) * 16;        // k-half (t even/odd pair covers 128B contiguous)
    const int sac   = t & 63;              // anchor id
    const int sak   = (t >> 6) * 8;        // k-offset 0/8/16/24

    if (t < CC) an2s[t] = anorm2[t];

    const float* xp = x + (size_t)(brow + sxrow) * DD + sxk;
    const float* ap = anchors + (size_t)sac * DD + sak;

    // chunk-0 prefetch into registers
    float4 xr0 = *(const float4*)(xp + 0);
    float4 xr1 = *(const float4*)(xp + 4);
    float4 xr2 = *(const float4*)(xp + 8);
    float4 xr3 = *(const float4*)(xp + 12);
    float4 ar0 = *(const float4*)(ap + 0);
    float4 ar1 = *(const float4*)(ap + 4);

    float acc[8][4] = {};
    float ssq = 0.f;

    for (int kb = 0; kb < DD; kb += BK) {
        // stage regs -> LDS (and fold this row-slice into ssq)
        ssq += xr0.x*xr0.x + xr0.y*xr0.y + xr0.z*xr0.z + xr0.w*xr0.w
             + xr1.x*xr1.x + xr1.y*xr1.y + xr1.z*xr1.z + xr1.w*xr1.w
             + xr2.x*xr2.x + xr2.y*xr2.y + xr2.z*xr2.z + xr2.w*xr2.w
             + xr3.x*xr3.x + xr3.y*xr3.y + xr3.z*xr3.z + xr3.w*xr3.w;
        xt[sxk +  0][sxrow] = xr0.x; xt[sxk +  1][sxrow] = xr0.y;
        xt[sxk +  2][sxrow] = xr0.z; xt[sxk +  3][sxrow] = xr0.w;
        xt[sxk +  4][sxrow] = xr1.x; xt[sxk +  5][sxrow] = xr1.y;
        xt[sxk +  6][sxrow] = xr1.z; xt[sxk +  7][sxrow] = xr1.w;
        xt[sxk +  8][sxrow] = xr2.x; xt[sxk +  9][sxrow] = xr2.y;
        xt[sxk + 10][sxrow] = xr2.z; xt[sxk + 11][sxrow] = xr2.w;
        xt[sxk + 12][sxrow] = xr3.x; xt[sxk + 13][sxrow] = xr3.y;
        xt[sxk + 14][sxrow] = xr3.z; xt[sxk + 15][sxrow] = xr3.w;
        at[sak + 0][sac] = ar0.x; at[sak + 1][sac] = ar0.y;
        at[sak + 2][sac] = ar0.z; at[sak + 3][sac] = ar0.w;
        at[sak + 4][sac] = ar1.x; at[sak + 5][sac] = ar1.y;
        at[sak + 6][sac] = ar1.z; at[sak + 7][sac] = ar1.w;
        __syncthreads();
        if (kb + BK < DD) {   // prefetch next chunk (hides HBM latency under compute)
            xr0 = *(const float4*)(xp + kb + BK + 0);
            xr1 = *(const float4*)(xp + kb + BK + 4);
            xr2 = *(const float4*)(xp + kb + BK + 8);
            xr3 = *(const float4*)(xp + kb + BK + 12);
            ar0 = *(const float4*)(ap + kb + BK + 0);
            ar1 = *(const float4*)(ap + kb + BK + 4);
        }
        #pragma unroll
        for (int k = 0; k < BK; ++k) {
            float4 x0 = *(const float4*)&xt[k][tm * 8];
            float4 x1 = *(const float4*)&xt[k][tm * 8 + 4];
            float4 a0 = *(const float4*)&at[k][tc * 4];
            float xv[8] = {x0.x, x0.y, x0.z, x0.w, x1.x, x1.y, x1.z, x1.w};
            float av[4] = {a0.x, a0.y, a0.z, a0.w};
            #pragma unroll
            for (int i = 0; i < 8; ++i)
                #pragma unroll
                for (int j = 0; j < 4; ++j)
                    acc[i][j] += xv[i] * av[j];
        }
        __syncthreads();
    }

    // row sum-of-squares: even/odd stager pair holds the two k-halves
    ssq += __shfl_xor(ssq, 1);
    if ((t & 1) == 0) rssq[sxrow] = ssq;
    __syncthreads();

    const int mval = mask[b];

    #pragma unroll
    for (int i = 0; i < 8; ++i) {
        const int R = tm * 8 + i;
        const int n = n0 + R;
        const float ss   = rssq[R];
        const float inv  = 1.0f / fmaxf(sqrtf(ss), 1e-12f);   // F.normalize eps
        const float ssqn = ss * inv * inv;                    // == sum(xn*xn)

        float v[4];
        #pragma unroll
        for (int j = 0; j < 4; ++j) {
            const int c = tc * 4 + j;
            float sq = fmaxf(ssqn + an2s[c] - 2.0f * (acc[i][j] * inv), 0.0f);
            v[j] = 1.0f / sqrtf(sq);
        }
        float vmax = fmaxf(fmaxf(v[0], v[1]), fmaxf(v[2], v[3]));
        #pragma unroll
        for (int d = 1; d <= 8; d <<= 1) vmax = fmaxf(vmax, __shfl_xor(vmax, d));

        float e[4]; float s = 0.f;
        #pragma unroll
        for (int j = 0; j < 4; ++j) { e[j] = __expf(v[j] - vmax); s += e[j]; }
        #pragma unroll
        for (int d = 1; d <= 8; d <<= 1) s += __shfl_xor(s, d);
        const float rs = 1.0f / s;

        // argmax (ascending c local, strict > keeps FIRST max like jnp.argmax)
        float bv = v[0]; int bc = tc * 4;
        #pragma unroll
        for (int j = 1; j < 4; ++j)
            if (v[j] > bv) { bv = v[j]; bc = tc * 4 + j; }
        #pragma unroll
        for (int d = 1; d <= 8; d <<= 1) {
            float ov = __shfl_xor(bv, d);
            int   oc = __shfl_xor(bc, d);
            if (ov > bv || (ov == bv && oc < bc)) { bv = ov; bc = oc; }
        }

        const bool valid = (n < mval);
        const float vm = valid ? 1.0f : 0.0f;     // invalid rows -> score 0
        float4 sv = make_float4(e[0] * rs * vm, e[1] * rs * vm,
                                e[2] * rs * vm, e[3] * rs * vm);
        *(float4*)&scores[((size_t)(b * NN + n)) * CC + tc * 4] = sv;

        if (tc == 0) {
            invn[(size_t)b * NN + n] = inv;
            if (valid) atomicAdd(&counts[b * CC + bc], 1);
        }
    }
}

// ---------------- k2: per-batch mode cluster (argmax of counts, first-index tie) ----------------
__global__ void k2_index(const int* __restrict__ counts, int* __restrict__ index)
{
    const int c = threadIdx.x;   // 64 threads = 1 wave
    for (int b = 0; b < BB; ++b) {
        int cnt = counts[b * CC + c];
        int bc = c;
        #pragma unroll
        for (int d = 1; d < 64; d <<= 1) {
            int ocnt = __shfl_xor(cnt, d);
            int oc   = __shfl_xor(bc, d);
            if (ocnt > cnt || (ocnt == cnt && oc < bc)) { cnt = ocnt; bc = oc; }
        }
        if (c == 0) index[b] = bc;
    }
}

// ---------------- k3: feature[b][d] = sum_n x[b][n][d] * inv[n] * score[b][n][index[b]] ----------------
constexpr int K3_ROWS = 64;
constexpr int K3_BLOCKS = MROWS / K3_ROWS;   // 2048 (8 blocks/CU)
__global__ __launch_bounds__(256) void k3_feature(
    const float* __restrict__ x, const float* __restrict__ scores,
    const float* __restrict__ invn, const int* __restrict__ index,
    float* __restrict__ out)
{
    __shared__ float w[K3_ROWS];
    const int t   = threadIdx.x;
    const int blk = blockIdx.x;
    const int b   = blk >> 6;                  // 64 blocks per batch
    const int n0  = (blk & 63) * K3_ROWS;
    const int idx = index[b];
    if (t < K3_ROWS) {
        const int n = n0 + t;
        w[t] = scores[((size_t)(b * NN + n)) * CC + idx] * invn[(size_t)b * NN + n];
    }
    __syncthreads();

    const int d0 = (t & 127) * 4;              // 128 d-quads cover D=512
    const int rh = (t >> 7) * 32;              // row half
    const float* xb = x + ((size_t)b * NN + n0 + rh) * DD + d0;
    float a0 = 0.f, a1 = 0.f, a2 = 0.f, a3 = 0.f;
    #pragma unroll 8
    for (int r = 0; r < 32; ++r) {
        float4 xv = *(const float4*)(xb + (size_t)r * DD);   // wave: 1KB contiguous
        float ww = w[rh + r];
        a0 += xv.x * ww; a1 += xv.y * ww; a2 += xv.z * ww; a3 += xv.w * ww;
    }
    atomicAdd(&out[b * DD + d0 + 0], a0);
    atomicAdd(&out[b * DD + d0 + 1], a1);
    atomicAdd(&out[b * DD + d0 + 2], a2);
    atomicAdd(&out[b * DD + d0 + 3], a3);
}

// ---------------- launcher ----------------
extern "C" void kernel_launch(void* const* d_in, const int* in_sizes, int n_in,
                              void* d_out, int out_size, void* d_ws, size_t ws_size,
                              hipStream_t stream)
{
    const float* x       = (const float*)d_in[0];
    const int*   mask    = (const int*)d_in[1];
    const float* anchors = (const float*)d_in[2];
    float* out = (float*)d_out;

    float* wsf     = (float*)d_ws;
    float* scores  = wsf + WS_SCORES;
    float* invn    = wsf + WS_INVN;
    int*   counts  = (int*)(wsf + WS_COUNTS);
    int*   index   = (int*)(wsf + WS_INDEX);
    float* anorm2  = wsf + WS_ANORM;

    hipLaunchKernelGGL(k0_init,   dim3(64),        dim3(256), 0, stream,
                       anchors, out, counts, anorm2);
    hipLaunchKernelGGL(k1_scores, dim3(NBLK1),     dim3(256), 0, stream,
                       x, mask, anchors, anorm2, scores, invn, counts);
    hipLaunchKernelGGL(k2_index,  dim3(1),         dim3(64),  0, stream,
                       counts, index);
    hipLaunchKernelGGL(k3_feature, dim3(K3_BLOCKS), dim3(256), 0, stream,
                       x, scores, invn, index, out);
}